// Round 14
// baseline (200.198 us; speedup 1.0000x reference)
//
#include <hip/hip_runtime.h>
#include <hip/hip_fp16.h>
#include <hip/hip_cooperative_groups.h>
#include <cstdint>
#include <cstddef>

// z = soft_thresh(Toeplitz(v) @ x + W2 @ y, beta) -- complex, N=1024, M=256, B=1024
// Real embedding: C[1024][2048] = A'[1024][2560] @ B'[2560][2048] (layouts R0-R5).
// Output = Re(z) only: [1024,1024] f32 (R4 finding).
//
// R14 (R13 budget: ~15-20us of dispatch gaps left; kernels already lean):
//  ONE cooperative dispatch: phase1 = build (5 virtual build-blocks per real
//  block), grid.sync() (agent-scope, once -- not R9's per-block fence storm),
//  phase2 = R13 gemm verbatim (64x64 tile, BK=128, dbuf LDS, 2-deep prefetch).
//  512 blocks x 256 thr, exactly co-resident (2/CU: 72.4KB LDS, ~150 VGPR).

#define K_DIM 2560
#define BETA_F 0.01f
#define EPS_F  1e-12f

typedef __attribute__((ext_vector_type(8))) _Float16 half8;
typedef __attribute__((ext_vector_type(4))) _Float16 half4;
typedef __attribute__((ext_vector_type(4))) float   floatx4;

__device__ alignas(16) _Float16 g_Ap[1024 * K_DIM];      // 5 MB
__device__ alignas(16) _Float16 g_Bt[2048 * K_DIM];      // 10 MB

namespace cg = cooperative_groups;

__global__ __launch_bounds__(256, 2) void mega(
    const float* __restrict__ v_re, const float* __restrict__ v_im,
    const float* __restrict__ W2_re, const float* __restrict__ W2_im,
    const float* __restrict__ x_re, const float* __restrict__ x_im,
    const float* __restrict__ y_re, const float* __restrict__ y_im,
    float* __restrict__ out, int out_n)
{
    __shared__ __align__(16) _Float16 As[2 * 4 * 64 * 32];  // 32 KB
    __shared__ __align__(16) _Float16 Bs[2 * 4 * 64 * 32];  // 32 KB
    __shared__ float lre[32][33];                            // build scratch
    __shared__ float lim[32][33];

    const int tid = threadIdx.x;
    const int bid = blockIdx.x;          // 0..511

    // ================= phase 1: build A' and B' (5 virtual blocks) ==========
    for (int r = 0; r < 5; ++r) {
        const int vb = bid + 512 * r;    // virtual build-block 0..2559
        if (vb < 1280) {
            // ---- A' part: one thread per 8 halves (16B store) ----
            int t = vb * 256 + tid;
            int i  = t / 320;
            int c  = t - i * 320;
            int kp = c * 8;
            half8 h;
            if (kp < 1024) {
#pragma unroll
                for (int j = 0; j < 8; ++j) h[j] = (_Float16)v_re[1023 + i - kp - j];
            } else if (kp < 1280) {
                const float* s = W2_re + i * 256 + (kp - 1024);
#pragma unroll
                for (int j = 0; j < 8; ++j) h[j] = (_Float16)s[j];
            } else if (kp < 2304) {
                int k2 = kp - 1280;
#pragma unroll
                for (int j = 0; j < 8; ++j) h[j] = (_Float16)v_im[1023 + i - k2 - j];
            } else {
                const float* s = W2_im + i * 256 + (kp - 2304);
#pragma unroll
                for (int j = 0; j < 8; ++j) h[j] = (_Float16)s[j];
            }
            *reinterpret_cast<half8*>(g_Ap + (size_t)i * K_DIM + kp) = h;
        } else {
            // ---- B' part: transposing build ----
            int idx = vb - 1280;               // 0..1279
            int bk  = idx % 40;
            int by  = idx / 40;
            const float* sre = (bk < 32) ? x_re : y_re;
            const float* sim = (bk < 32) ? x_im : y_im;
            int kb   = (bk < 32) ? bk : (bk - 32);
            int koff = (bk < 32) ? 0 : 1024;
            int k0 = kb * 32;
            int n0 = by * 32;
            int tx = tid & 31, ty = tid >> 5;
#pragma unroll
            for (int s = 0; s < 4; ++s) {
                int kk = ty + 8 * s;
                lre[kk][tx] = sre[(size_t)(k0 + kk) * 1024 + n0 + tx];
                lim[kk][tx] = sim[(size_t)(k0 + kk) * 1024 + n0 + tx];
            }
            __syncthreads();
            int lane_n = tid >> 3;
            int kq     = (tid & 7) * 4;
            half4 hre, him, hmim;
#pragma unroll
            for (int j = 0; j < 4; ++j) {
                float re = lre[kq + j][lane_n];
                float im = lim[kq + j][lane_n];
                hre[j]  = (_Float16)re;
                him[j]  = (_Float16)im;
                hmim[j] = (_Float16)(-im);
            }
            int n = n0 + lane_n;
            size_t kk2 = (size_t)koff + k0 + kq;
            _Float16* r0 = g_Bt + (size_t)(2 * n)     * K_DIM;
            _Float16* r1 = g_Bt + (size_t)(2 * n + 1) * K_DIM;
            *reinterpret_cast<half4*>(r0 + kk2)        = hre;
            *reinterpret_cast<half4*>(r0 + kk2 + 1280) = hmim;
            *reinterpret_cast<half4*>(r1 + kk2)        = him;
            *reinterpret_cast<half4*>(r1 + kk2 + 1280) = hre;
        }
        __syncthreads();                 // protect lre/lim reuse across r
    }

    // ================= grid-wide barrier (device-scope visibility) ==========
    cg::this_grid().sync();

    // ================= phase 2: gemm + fused soft-threshold (R13) ===========
    const int lane = tid & 63;
    const int w    = tid >> 6;
    const int wm   = w >> 1;
    const int wn   = w & 1;

    const int xcd = bid & 7;
    const int t   = bid >> 3;
    const int mi0 = ((xcd & 1) * 8 + (t & 7)) * 64;
    const int ni0 = ((xcd >> 1) * 8 + (t >> 3)) * 64;

    floatx4 acc[2][2];
#pragma unroll
    for (int a = 0; a < 2; ++a)
#pragma unroll
        for (int b = 0; b < 2; ++b) acc[a][b] = (floatx4)0.0f;

    const int rS = tid >> 2;
    const int jS = tid & 3;
    const int s0 = ((rS & 15) >> 1) & 3;
    char* asW = (char*)As + rS * 64 + ((jS ^ s0) * 16);
    char* bsW = (char*)Bs + rS * 64 + ((jS ^ s0) * 16);
    const _Float16* gA = g_Ap + (size_t)(mi0 + rS) * K_DIM + jS * 8;
    const _Float16* gB = g_Bt + (size_t)(ni0 + rS) * K_DIM + jS * 8;

    const int rowA = lane & 15;
    const int q    = lane >> 4;
    const int coff = (q ^ ((rowA >> 1) & 3)) * 16;

    const int NIT = K_DIM / 128;         // 20
    half8 sA[2][4], sB[2][4];

    {   // prologue: slab 0 -> LDS buf 0; slab 1 -> set[1]
        half8 tA[4], tB[4];
#pragma unroll
        for (int ks = 0; ks < 4; ++ks) {
            tA[ks] = *reinterpret_cast<const half8*>(gA + ks * 32);
            tB[ks] = *reinterpret_cast<const half8*>(gB + ks * 32);
        }
#pragma unroll
        for (int ks = 0; ks < 4; ++ks) {
            sA[1][ks] = *reinterpret_cast<const half8*>(gA + 128 + ks * 32);
            sB[1][ks] = *reinterpret_cast<const half8*>(gB + 128 + ks * 32);
        }
#pragma unroll
        for (int ks = 0; ks < 4; ++ks) {
            *reinterpret_cast<half8*>(asW + ks * 4096) = tA[ks];
            *reinterpret_cast<half8*>(bsW + ks * 4096) = tB[ks];
        }
    }
    __syncthreads();

#pragma unroll 2
    for (int kt = 0; kt < NIT; ++kt) {
        const int cur = kt & 1;
        const int nxt = cur ^ 1;
        if (kt + 2 < NIT) {
            const _Float16* ga = gA + (size_t)(kt + 2) * 128;
            const _Float16* gb = gB + (size_t)(kt + 2) * 128;
#pragma unroll
            for (int ks = 0; ks < 4; ++ks) {
                sA[cur][ks] = *reinterpret_cast<const half8*>(ga + ks * 32);
                sB[cur][ks] = *reinterpret_cast<const half8*>(gb + ks * 32);
            }
        }
        const char* Ab = (const char*)As + cur * 16384;
        const char* Bb = (const char*)Bs + cur * 16384;
#pragma unroll
        for (int ks = 0; ks < 4; ++ks) {
            half8 af[2], bf[2];
#pragma unroll
            for (int mi = 0; mi < 2; ++mi) {
                int rr = wm * 32 + mi * 16 + rowA;
                af[mi] = *reinterpret_cast<const half8*>(Ab + ks * 4096 + rr * 64 + coff);
            }
#pragma unroll
            for (int ni = 0; ni < 2; ++ni) {
                int rr = wn * 32 + ni * 16 + rowA;
                bf[ni] = *reinterpret_cast<const half8*>(Bb + ks * 4096 + rr * 64 + coff);
            }
#pragma unroll
            for (int mi = 0; mi < 2; ++mi)
#pragma unroll
                for (int ni = 0; ni < 2; ++ni)
                    acc[mi][ni] = __builtin_amdgcn_mfma_f32_16x16x32_f16(
                        af[mi], bf[ni], acc[mi][ni], 0, 0, 0);
        }
        if (kt + 1 < NIT) {
            char* aw = asW + nxt * 16384;
            char* bw = bsW + nxt * 16384;
#pragma unroll
            for (int ks = 0; ks < 4; ++ks) {
                *reinterpret_cast<half8*>(aw + ks * 4096) = sA[nxt][ks];
                *reinterpret_cast<half8*>(bw + ks * 4096) = sB[nxt][ks];
            }
        }
        __syncthreads();
    }

    // epilogue: C/D col=lane&15, row=(lane>>4)*4+reg; lane^1 = re/im partner.
    const int colL  = lane & 15;
    const int rquad = (lane >> 4) * 4;
#pragma unroll
    for (int mi = 0; mi < 2; ++mi)
#pragma unroll
        for (int ni = 0; ni < 2; ++ni)
#pragma unroll
            for (int rr = 0; rr < 4; ++rr) {
                float c = acc[mi][ni][rr];
                float p = __shfl_xor(c, 1, 64);
                float mag = sqrtf(c * c + p * p);
                float s = fmaxf(mag - BETA_F, 0.0f) / fmaxf(mag, EPS_F);
                int row = mi0 + wm * 32 + mi * 16 + rquad + rr;
                int col = ni0 + wn * 32 + ni * 16 + colL;
                if ((col & 1) == 0) {
                    size_t idx = (size_t)row * 1024 + (col >> 1);
                    if (idx < (size_t)out_n) out[idx] = c * s;
                }
            }
}

// ---------------- launcher ---------------------------------------------------
extern "C" void kernel_launch(void* const* d_in, const int* in_sizes, int n_in,
                              void* d_out, int out_size, void* d_ws, size_t ws_size,
                              hipStream_t stream) {
    (void)d_ws; (void)ws_size; (void)in_sizes; (void)n_in;
    const float* v_re  = (const float*)d_in[0];
    const float* v_im  = (const float*)d_in[1];
    const float* W2_re = (const float*)d_in[2];
    const float* W2_im = (const float*)d_in[3];
    const float* x_re  = (const float*)d_in[4];
    const float* x_im  = (const float*)d_in[5];
    const float* y_re  = (const float*)d_in[6];
    const float* y_im  = (const float*)d_in[7];
    float* out = (float*)d_out;
    int out_n = out_size;

    void* args[] = { &v_re, &v_im, &W2_re, &W2_im,
                     &x_re, &x_im, &y_re, &y_im, &out, &out_n };
    hipLaunchCooperativeKernel((void*)mega, dim3(512), dim3(256),
                               args, 0, stream);
}

// Round 15
// 158.503 us; speedup vs baseline: 1.2631x; 1.2631x over previous
//
#include <hip/hip_runtime.h>
#include <hip/hip_fp16.h>
#include <cstdint>
#include <cstddef>

// z = soft_thresh(Toeplitz(v) @ x + W2 @ y, beta) -- complex, N=1024, M=256, B=1024
// Real embedding: C[1024][2048] = A'[1024][2560] @ B'[2560][2048] (layouts R0-R5).
// Output = Re(z) only: [1024,1024] f32 (R4 finding).
//
// R15 (R14 cooperative failed -> revert to 2 dispatches; attack the barrier-
// drain structurally): gemm with NO LDS AND NO BARRIERS. Each lane loads its
// MFMA fragments (16B k-contiguous) directly from global; 4-deep register
// pipeline (slot = ksub & 3) keeps ~16 loads in flight; compiler emits
// fine-grained vmcnt (never a full drain). Wave-pair L1 reuse replaces LDS
// sharing (wn-pair shares A frags, wm-pair shares B frags).

#define K_DIM 2560
#define BETA_F 0.01f
#define EPS_F  1e-12f

typedef __attribute__((ext_vector_type(8))) _Float16 half8;
typedef __attribute__((ext_vector_type(4))) _Float16 half4;
typedef __attribute__((ext_vector_type(4))) float   floatx4;

__device__ alignas(16) _Float16 g_Ap[1024 * K_DIM];      // 5 MB
__device__ alignas(16) _Float16 g_Bt[2048 * K_DIM];      // 10 MB

// ---------------- prep (merged): build A' and B' (identical to R13) ----------
__global__ __launch_bounds__(256) void build_all(
    const float* __restrict__ v_re, const float* __restrict__ v_im,
    const float* __restrict__ W2_re, const float* __restrict__ W2_im,
    const float* __restrict__ x_re, const float* __restrict__ x_im,
    const float* __restrict__ y_re, const float* __restrict__ y_im)
{
    const int bx = blockIdx.x;
    if (bx < 1280) {
        int t = bx * 256 + threadIdx.x;
        int i  = t / 320;
        int c  = t - i * 320;
        int kp = c * 8;                        // segment-aligned
        half8 h;
        if (kp < 1024) {
#pragma unroll
            for (int j = 0; j < 8; ++j) h[j] = (_Float16)v_re[1023 + i - kp - j];
        } else if (kp < 1280) {
            const float* s = W2_re + i * 256 + (kp - 1024);
#pragma unroll
            for (int j = 0; j < 8; ++j) h[j] = (_Float16)s[j];
        } else if (kp < 2304) {
            int k2 = kp - 1280;
#pragma unroll
            for (int j = 0; j < 8; ++j) h[j] = (_Float16)v_im[1023 + i - k2 - j];
        } else {
            const float* s = W2_im + i * 256 + (kp - 2304);
#pragma unroll
            for (int j = 0; j < 8; ++j) h[j] = (_Float16)s[j];
        }
        *reinterpret_cast<half8*>(g_Ap + (size_t)i * K_DIM + kp) = h;
        return;
    }
    __shared__ float lre[32][33];
    __shared__ float lim[32][33];
    int idx = bx - 1280;                       // 0..1279
    int bk  = idx % 40;
    int by  = idx / 40;
    const float* sre = (bk < 32) ? x_re : y_re;
    const float* sim = (bk < 32) ? x_im : y_im;
    int kb   = (bk < 32) ? bk : (bk - 32);
    int koff = (bk < 32) ? 0 : 1024;
    int k0 = kb * 32;
    int n0 = by * 32;
    int tid = threadIdx.x;
    int tx = tid & 31, ty = tid >> 5;
#pragma unroll
    for (int s = 0; s < 4; ++s) {
        int kk = ty + 8 * s;
        lre[kk][tx] = sre[(size_t)(k0 + kk) * 1024 + n0 + tx];
        lim[kk][tx] = sim[(size_t)(k0 + kk) * 1024 + n0 + tx];
    }
    __syncthreads();
    int lane_n = tid >> 3;
    int kq     = (tid & 7) * 4;
    half4 hre, him, hmim;
#pragma unroll
    for (int j = 0; j < 4; ++j) {
        float re = lre[kq + j][lane_n];
        float im = lim[kq + j][lane_n];
        hre[j]  = (_Float16)re;
        him[j]  = (_Float16)im;
        hmim[j] = (_Float16)(-im);
    }
    int n = n0 + lane_n;
    size_t kk2 = (size_t)koff + k0 + kq;
    _Float16* r0 = g_Bt + (size_t)(2 * n)     * K_DIM;
    _Float16* r1 = g_Bt + (size_t)(2 * n + 1) * K_DIM;
    *reinterpret_cast<half4*>(r0 + kk2)        = hre;
    *reinterpret_cast<half4*>(r0 + kk2 + 1280) = hmim;
    *reinterpret_cast<half4*>(r1 + kk2)        = him;
    *reinterpret_cast<half4*>(r1 + kk2 + 1280) = hre;
}

// ---------------- barrier-free direct-streaming GEMM + soft-threshold -------
// 64x64 tile, 512 blocks, 4 waves (2x2 of 32x32). NO LDS, NO __syncthreads.
// Per ksub (32k): lane loads af[2], bf[2] (16B each, k-contiguous) directly
// from global; 4-deep slot pipeline keeps 16 loads in flight.
__global__ __launch_bounds__(256, 4) void gemm_fused(float* __restrict__ out,
                                                     int out_n)
{
    const int tid  = threadIdx.x;
    const int lane = tid & 63;
    const int w    = tid >> 6;
    const int wm   = w >> 1;
    const int wn   = w & 1;

    const int bid = blockIdx.x;          // 0..511
    const int xcd = bid & 7;             // round-robin -> XCD; 8x8 super-tile
    const int t   = bid >> 3;            // 0..63
    const int mi0 = ((xcd & 1) * 8 + (t & 7)) * 64;       // 0..960
    const int ni0 = ((xcd >> 1) * 8 + (t >> 3)) * 64;     // 0..1984

    const int rowA = lane & 15;
    const int q8   = (lane >> 4) * 8;    // k sub-offset within ksub

    // per-lane fragment base pointers (k-contiguous 16B chunks)
    const _Float16* aP[2];
    const _Float16* bP[2];
#pragma unroll
    for (int mi = 0; mi < 2; ++mi)
        aP[mi] = g_Ap + (size_t)(mi0 + wm * 32 + mi * 16 + rowA) * K_DIM + q8;
#pragma unroll
    for (int ni = 0; ni < 2; ++ni)
        bP[ni] = g_Bt + (size_t)(ni0 + wn * 32 + ni * 16 + rowA) * K_DIM + q8;

    floatx4 acc[2][2];
#pragma unroll
    for (int a = 0; a < 2; ++a)
#pragma unroll
        for (int b = 0; b < 2; ++b) acc[a][b] = (floatx4)0.0f;

    const int NKS = K_DIM / 32;          // 80 ksubs

    half8 pa[4][2], pb[4][2];            // 4-deep pipeline slots
#pragma unroll
    for (int s = 0; s < 4; ++s) {
#pragma unroll
        for (int mi = 0; mi < 2; ++mi)
            pa[s][mi] = *reinterpret_cast<const half8*>(aP[mi] + s * 32);
#pragma unroll
        for (int ni = 0; ni < 2; ++ni)
            pb[s][ni] = *reinterpret_cast<const half8*>(bP[ni] + s * 32);
    }

#pragma unroll 4
    for (int s = 0; s < NKS; ++s) {
        const int slot = s & 3;
#pragma unroll
        for (int mi = 0; mi < 2; ++mi)
#pragma unroll
            for (int ni = 0; ni < 2; ++ni)
                acc[mi][ni] = __builtin_amdgcn_mfma_f32_16x16x32_f16(
                    pa[slot][mi], pb[slot][ni], acc[mi][ni], 0, 0, 0);
        if (s + 4 < NKS) {               // refill slot with ksub s+4
#pragma unroll
            for (int mi = 0; mi < 2; ++mi)
                pa[slot][mi] = *reinterpret_cast<const half8*>(aP[mi] + (s + 4) * 32);
#pragma unroll
            for (int ni = 0; ni < 2; ++ni)
                pb[slot][ni] = *reinterpret_cast<const half8*>(bP[ni] + (s + 4) * 32);
        }
    }

    // epilogue: C/D col=lane&15, row=(lane>>4)*4+reg; lane^1 = re/im partner.
    // Output = Re(z) only: even C'-columns -> out[row*1024 + col/2].
    const int colL  = lane & 15;
    const int rquad = (lane >> 4) * 4;
#pragma unroll
    for (int mi = 0; mi < 2; ++mi)
#pragma unroll
        for (int ni = 0; ni < 2; ++ni)
#pragma unroll
            for (int r = 0; r < 4; ++r) {
                float c = acc[mi][ni][r];
                float p = __shfl_xor(c, 1, 64);
                float mag = sqrtf(c * c + p * p);
                float sc = fmaxf(mag - BETA_F, 0.0f) / fmaxf(mag, EPS_F);
                int row = mi0 + wm * 32 + mi * 16 + rquad + r;
                int col = ni0 + wn * 32 + ni * 16 + colL;   // C' col (0..2047)
                if ((col & 1) == 0) {                        // even = Re lane
                    size_t idx = (size_t)row * 1024 + (col >> 1);
                    if (idx < (size_t)out_n) out[idx] = c * sc;
                }
            }
}

// ---------------- launcher ---------------------------------------------------
extern "C" void kernel_launch(void* const* d_in, const int* in_sizes, int n_in,
                              void* d_out, int out_size, void* d_ws, size_t ws_size,
                              hipStream_t stream) {
    (void)d_ws; (void)ws_size; (void)in_sizes; (void)n_in;
    const float* v_re  = (const float*)d_in[0];
    const float* v_im  = (const float*)d_in[1];
    const float* W2_re = (const float*)d_in[2];
    const float* W2_im = (const float*)d_in[3];
    const float* x_re  = (const float*)d_in[4];
    const float* x_im  = (const float*)d_in[5];
    const float* y_re  = (const float*)d_in[6];
    const float* y_im  = (const float*)d_in[7];
    float* out = (float*)d_out;

    build_all<<<2560, 256, 0, stream>>>(v_re, v_im, W2_re, W2_im,
                                        x_re, x_im, y_re, y_im);
    gemm_fused<<<512, 256, 0, stream>>>(out, out_size);
}

// Round 16
// 109.137 us; speedup vs baseline: 1.8344x; 1.4523x over previous
//
#include <hip/hip_runtime.h>
#include <hip/hip_fp16.h>
#include <cstdint>
#include <cstddef>

// z = soft_thresh(Toeplitz(v) @ x + W2 @ y, beta) -- complex, N=1024, M=256, B=1024
// Real embedding: C[1024][2048] = A'[1024][2560] @ B'[2560][2048] (layouts R0-R5).
// Output = Re(z) only: [1024,1024] f32 (R4 finding).
//
// R16 (R15 no-LDS failed -> revert to R13 core; halve the B operand):
//  g_Bc[2][1024][1280] stores only re/im planes of [x;y]^T (5 MB, was 10).
//  The duplicated/negated Bt rows are reconstructed at LDS-staging time:
//  plane = (rS&1)^half, negate = (second half && even row). LDS contents are
//  bit-identical to R13 -> ds_read / MFMA / epilogue untouched.

#define K_DIM 2560
#define BPLANE (1024 * 1280)
#define BETA_F 0.01f
#define EPS_F  1e-12f

typedef __attribute__((ext_vector_type(8))) _Float16 half8;
typedef __attribute__((ext_vector_type(4))) _Float16 half4;
typedef __attribute__((ext_vector_type(4))) float   floatx4;

__device__ alignas(16) _Float16 g_Ap[1024 * K_DIM];      // 5 MB
__device__ alignas(16) _Float16 g_Bc[2 * BPLANE];        // 5 MB [plane][n][k]

__device__ __forceinline__ half8 negh8(half8 v, bool neg) {
    if (!neg) return v;
    union { half8 h; unsigned u[4]; } t; t.h = v;
#pragma unroll
    for (int i = 0; i < 4; ++i) t.u[i] ^= 0x80008000u;
    return t.h;
}

// ---------------- prep (merged): build A' and B planes -----------------------
__global__ __launch_bounds__(256) void build_all(
    const float* __restrict__ v_re, const float* __restrict__ v_im,
    const float* __restrict__ W2_re, const float* __restrict__ W2_im,
    const float* __restrict__ x_re, const float* __restrict__ x_im,
    const float* __restrict__ y_re, const float* __restrict__ y_im)
{
    const int bx = blockIdx.x;
    if (bx < 1280) {
        // ---- A' part: one thread per 8 halves (16B store) ----
        int t = bx * 256 + threadIdx.x;
        int i  = t / 320;
        int c  = t - i * 320;
        int kp = c * 8;                        // segment-aligned
        half8 h;
        if (kp < 1024) {
#pragma unroll
            for (int j = 0; j < 8; ++j) h[j] = (_Float16)v_re[1023 + i - kp - j];
        } else if (kp < 1280) {
            const float* s = W2_re + i * 256 + (kp - 1024);
#pragma unroll
            for (int j = 0; j < 8; ++j) h[j] = (_Float16)s[j];
        } else if (kp < 2304) {
            int k2 = kp - 1280;
#pragma unroll
            for (int j = 0; j < 8; ++j) h[j] = (_Float16)v_im[1023 + i - k2 - j];
        } else {
            const float* s = W2_im + i * 256 + (kp - 2304);
#pragma unroll
            for (int j = 0; j < 8; ++j) h[j] = (_Float16)s[j];
        }
        *reinterpret_cast<half8*>(g_Ap + (size_t)i * K_DIM + kp) = h;
        return;
    }
    // ---- B part: transposing build of the two planes ----
    __shared__ float lre[32][33];
    __shared__ float lim[32][33];
    int idx = bx - 1280;                       // 0..1279
    int bk  = idx % 40;                        // k-block / source select
    int by  = idx / 40;                        // n-block 0..31
    const float* sre = (bk < 32) ? x_re : y_re;
    const float* sim = (bk < 32) ? x_im : y_im;
    int kb   = (bk < 32) ? bk : (bk - 32);
    int koff = (bk < 32) ? 0 : 1024;
    int k0 = kb * 32;
    int n0 = by * 32;
    int tid = threadIdx.x;
    int tx = tid & 31, ty = tid >> 5;
#pragma unroll
    for (int s = 0; s < 4; ++s) {
        int kk = ty + 8 * s;
        lre[kk][tx] = sre[(size_t)(k0 + kk) * 1024 + n0 + tx];
        lim[kk][tx] = sim[(size_t)(k0 + kk) * 1024 + n0 + tx];
    }
    __syncthreads();
    int lane_n = tid >> 3;                     // 0..31
    int kq     = (tid & 7) * 4;                // 0,4,...,28
    half4 hre, him;
#pragma unroll
    for (int j = 0; j < 4; ++j) {
        hre[j] = (_Float16)lre[kq + j][lane_n];
        him[j] = (_Float16)lim[kq + j][lane_n];
    }
    int n = n0 + lane_n;
    size_t kk2 = (size_t)n * 1280 + koff + k0 + kq;
    *reinterpret_cast<half4*>(g_Bc + kk2)          = hre;   // re plane
    *reinterpret_cast<half4*>(g_Bc + BPLANE + kk2) = him;   // im plane
}

// ---------------- non-split GEMM + fused soft-threshold, BK=128 --------------
// 64x64 tile, BK=128 (10 first-half + 10 second-half slabs), 512 blocks (2/CU),
// 4 waves = 2x2 of 32x32. Dbuf LDS (1 barrier/iter), 2-deep register prefetch.
// B staged from planes: plane=(rS&1)^half, negate=(half && even row).
__global__ __launch_bounds__(256, 2) void gemm_fused(float* __restrict__ out,
                                                     int out_n)
{
    __shared__ __align__(16) _Float16 As[2 * 4 * 64 * 32];  // 32 KB
    __shared__ __align__(16) _Float16 Bs[2 * 4 * 64 * 32];  // 32 KB

    const int tid  = threadIdx.x;
    const int lane = tid & 63;
    const int w    = tid >> 6;
    const int wm   = w >> 1;
    const int wn   = w & 1;

    const int bid = blockIdx.x;          // 0..511
    const int xcd = bid & 7;             // round-robin -> XCD; 8x8 super-tile
    const int t   = bid >> 3;            // 0..63
    const int mi0 = ((xcd & 1) * 8 + (t & 7)) * 64;       // 0..960
    const int ni0 = ((xcd >> 1) * 8 + (t >> 3)) * 64;     // 0..1984

    floatx4 acc[2][2];
#pragma unroll
    for (int a = 0; a < 2; ++a)
#pragma unroll
        for (int b = 0; b < 2; ++b) acc[a][b] = (floatx4)0.0f;

    const int rS = tid >> 2;                 // staging row 0..63
    const int jS = tid & 3;                  // 16B chunk in 64B sub-row
    const int s0 = ((rS & 15) >> 1) & 3;
    char* asW = (char*)As + rS * 64 + ((jS ^ s0) * 16);
    char* bsW = (char*)Bs + rS * 64 + ((jS ^ s0) * 16);
    const _Float16* gA = g_Ap + (size_t)(mi0 + rS) * K_DIM + jS * 8;
    const size_t bRow  = (size_t)(ni0 / 2 + (rS >> 1)) * 1280 + jS * 8;
    const int    rpar  = rS & 1;

    const int rowA = lane & 15;
    const int q    = lane >> 4;
    const int coff = (q ^ ((rowA >> 1) & 3)) * 16;

    const int NIT = K_DIM / 128;         // 20 slabs; slabs >=10 are second half

    // B source pointer for slab sl (handles plane select + k rebase)
    auto gbSlab = [&](int sl) -> const _Float16* {
        int hf = (sl >= 10);
        return g_Bc + (size_t)(rpar ^ hf) * BPLANE + bRow
                    + (size_t)sl * 128 - (size_t)hf * 1280;
    };

    half8 sA[2][4], sB[2][4];

    {   // prologue: slab 0 -> LDS buf 0; slab 1 -> set[1] (both first-half)
        const _Float16* gb0 = gbSlab(0);
        const _Float16* gb1 = gbSlab(1);
        half8 tA[4], tB[4];
#pragma unroll
        for (int ks = 0; ks < 4; ++ks) {
            tA[ks] = *reinterpret_cast<const half8*>(gA + ks * 32);
            tB[ks] = *reinterpret_cast<const half8*>(gb0 + ks * 32);
        }
#pragma unroll
        for (int ks = 0; ks < 4; ++ks) {
            sA[1][ks] = *reinterpret_cast<const half8*>(gA + 128 + ks * 32);
            sB[1][ks] = *reinterpret_cast<const half8*>(gb1 + ks * 32);
        }
#pragma unroll
        for (int ks = 0; ks < 4; ++ks) {
            *reinterpret_cast<half8*>(asW + ks * 4096) = tA[ks];
            *reinterpret_cast<half8*>(bsW + ks * 4096) = tB[ks];
        }
    }
    __syncthreads();

#pragma unroll 2
    for (int kt = 0; kt < NIT; ++kt) {
        const int cur = kt & 1;
        const int nxt = cur ^ 1;
        if (kt + 2 < NIT) {              // issue slab kt+2 into set[cur]
            const _Float16* ga = gA + (size_t)(kt + 2) * 128;
            const _Float16* gb = gbSlab(kt + 2);
#pragma unroll
            for (int ks = 0; ks < 4; ++ks) {
                sA[cur][ks] = *reinterpret_cast<const half8*>(ga + ks * 32);
                sB[cur][ks] = *reinterpret_cast<const half8*>(gb + ks * 32);
            }
        }
        const char* Ab = (const char*)As + cur * 16384;
        const char* Bb = (const char*)Bs + cur * 16384;
#pragma unroll
        for (int ks = 0; ks < 4; ++ks) {
            half8 af[2], bf[2];
#pragma unroll
            for (int mi = 0; mi < 2; ++mi) {
                int r = wm * 32 + mi * 16 + rowA;
                af[mi] = *reinterpret_cast<const half8*>(Ab + ks * 4096 + r * 64 + coff);
            }
#pragma unroll
            for (int ni = 0; ni < 2; ++ni) {
                int r = wn * 32 + ni * 16 + rowA;
                bf[ni] = *reinterpret_cast<const half8*>(Bb + ks * 4096 + r * 64 + coff);
            }
#pragma unroll
            for (int mi = 0; mi < 2; ++mi)
#pragma unroll
                for (int ni = 0; ni < 2; ++ni)
                    acc[mi][ni] = __builtin_amdgcn_mfma_f32_16x16x32_f16(
                        af[mi], bf[ni], acc[mi][ni], 0, 0, 0);
        }
        if (kt + 1 < NIT) {              // store slab kt+1 (apply sign fix-up)
            const bool neg = ((kt + 1) >= 10) && (rpar == 0);
            char* aw = asW + nxt * 16384;
            char* bw = bsW + nxt * 16384;
#pragma unroll
            for (int ks = 0; ks < 4; ++ks) {
                *reinterpret_cast<half8*>(aw + ks * 4096) = sA[nxt][ks];
                *reinterpret_cast<half8*>(bw + ks * 4096) = negh8(sB[nxt][ks], neg);
            }
        }
        __syncthreads();                 // single barrier per iter
    }

    // epilogue: C/D col=lane&15, row=(lane>>4)*4+reg; lane^1 = re/im partner.
    // Output = Re(z) only: even C'-columns -> out[row*1024 + col/2].
    const int colL  = lane & 15;
    const int rquad = (lane >> 4) * 4;
#pragma unroll
    for (int mi = 0; mi < 2; ++mi)
#pragma unroll
        for (int ni = 0; ni < 2; ++ni)
#pragma unroll
            for (int r = 0; r < 4; ++r) {
                float c = acc[mi][ni][r];
                float p = __shfl_xor(c, 1, 64);
                float mag = sqrtf(c * c + p * p);
                float s = fmaxf(mag - BETA_F, 0.0f) / fmaxf(mag, EPS_F);
                int row = mi0 + wm * 32 + mi * 16 + rquad + r;
                int col = ni0 + wn * 32 + ni * 16 + colL;   // C' col (0..2047)
                if ((col & 1) == 0) {                        // even = Re lane
                    size_t idx = (size_t)row * 1024 + (col >> 1);
                    if (idx < (size_t)out_n) out[idx] = c * s;
                }
            }
}

// ---------------- launcher ---------------------------------------------------
extern "C" void kernel_launch(void* const* d_in, const int* in_sizes, int n_in,
                              void* d_out, int out_size, void* d_ws, size_t ws_size,
                              hipStream_t stream) {
    (void)d_ws; (void)ws_size; (void)in_sizes; (void)n_in;
    const float* v_re  = (const float*)d_in[0];
    const float* v_im  = (const float*)d_in[1];
    const float* W2_re = (const float*)d_in[2];
    const float* W2_im = (const float*)d_in[3];
    const float* x_re  = (const float*)d_in[4];
    const float* x_im  = (const float*)d_in[5];
    const float* y_re  = (const float*)d_in[6];
    const float* y_im  = (const float*)d_in[7];
    float* out = (float*)d_out;

    build_all<<<2560, 256, 0, stream>>>(v_re, v_im, W2_re, W2_im,
                                        x_re, x_im, y_re, y_im);
    gemm_fused<<<512, 256, 0, stream>>>(out, out_size);
}